// Round 5
// baseline (143.538 us; speedup 1.0000x reference)
//
#include <hip/hip_runtime.h>
#include <hip/hip_bf16.h>

// x (32768,3072) f32, W1 (32,3072), b1 (32), W2 (10,32), b2 (10)
// out: (32768,10) f32 = sigmoid(relu(x@W1^T+b1)@W2^T+b2)
//
// Single-kernel version: no prep pass, W1 fp32 read in-loop (L2-hot),
// R2 core (best measured): 4 waves = 2 rowgroups x 2 k-halves, 32 rows/block.

typedef float  f32x4  __attribute__((ext_vector_type(4)));
typedef short  short8 __attribute__((ext_vector_type(8)));

#define IN_SIZE 3072
#define HIDDEN  32
#define OUTS    10
#define KSPLIT  2
#define KH      (IN_SIZE / 32 / KSPLIT)   // 48 K-steps per wave

__device__ __forceinline__ unsigned short f2bf(float f) {
    return __builtin_bit_cast(unsigned short, __float2bfloat16(f));
}

__device__ __forceinline__ short8 cvt8(f32x4 a, f32x4 b) {
    short8 r;
    r[0] = (short)f2bf(a[0]); r[1] = (short)f2bf(a[1]);
    r[2] = (short)f2bf(a[2]); r[3] = (short)f2bf(a[3]);
    r[4] = (short)f2bf(b[0]); r[5] = (short)f2bf(b[1]);
    r[6] = (short)f2bf(b[2]); r[7] = (short)f2bf(b[3]);
    return r;
}

__global__ __launch_bounds__(256, 4)
void mlp_one(const float* __restrict__ x,
             const float* __restrict__ W1,
             const float* __restrict__ b1,
             const float* __restrict__ W2,
             const float* __restrict__ b2,
             float* __restrict__ out) {
    // 2 rowgroups x 2 k-halves of partial h tiles (raw accumulators, no bias)
    __shared__ __align__(16) float hbuf[2][2][16][36];

    const int tid = threadIdx.x;
    const int l   = tid & 63;          // lane
    const int w   = tid >> 6;          // wave in block
    const int rg  = w >> 1;            // rowgroup (0..1)
    const int kh  = w & 1;             // k-half   (0..1)
    const int lr  = l & 15;            // A row within tile / B,C col
    const int kg  = l >> 4;            // k-group (0..3)
    const int rowbase = blockIdx.x * 32 + rg * 16;

    // A: lane (lr,kg), element j -> x[rowbase+lr][khbase + s*32 + kg*8 + j]
    // B: lane (lr,kg), element j -> W1[lr + 16*nt][khbase + s*32 + kg*8 + j]
    // (same mapping prep_w1 used in R1-R4; validated on HW)
    const int khbase = kh * (KH * 32);
    const float* xp  = x  + (size_t)(rowbase + lr) * IN_SIZE + khbase + kg * 8;
    const float* w0p = W1 + (size_t)lr * IN_SIZE        + khbase + kg * 8;
    const float* w1p = W1 + (size_t)(lr + 16) * IN_SIZE + khbase + kg * 8;

    f32x4 acc0 = {0.f, 0.f, 0.f, 0.f};   // h cols 0..15
    f32x4 acc1 = {0.f, 0.f, 0.f, 0.f};   // h cols 16..31

    // depth-2 register prefetch of the x stream (the HBM-bound operand);
    // W1 fragments loaded at use (L2-hot after first touch per XCD).
    f32x4 pa0 = *(const f32x4*)(xp);
    f32x4 pa1 = *(const f32x4*)(xp + 4);
    f32x4 qa0 = *(const f32x4*)(xp + 32);
    f32x4 qa1 = *(const f32x4*)(xp + 36);

    int s = 0;
    for (; s + 2 < KH; s += 2) {
        // ---- step s (uses pa; refill pa with s+2) ----
        f32x4 c0 = *(const f32x4*)(w0p + s * 32);
        f32x4 c1 = *(const f32x4*)(w0p + s * 32 + 4);
        f32x4 d0 = *(const f32x4*)(w1p + s * 32);
        f32x4 d1 = *(const f32x4*)(w1p + s * 32 + 4);
        short8 af = cvt8(pa0, pa1);
        pa0 = *(const f32x4*)(xp + (s + 2) * 32);
        pa1 = *(const f32x4*)(xp + (s + 2) * 32 + 4);
        short8 bf0 = cvt8(c0, c1);
        short8 bf1 = cvt8(d0, d1);
        acc0 = __builtin_amdgcn_mfma_f32_16x16x32_bf16(af, bf0, acc0, 0, 0, 0);
        acc1 = __builtin_amdgcn_mfma_f32_16x16x32_bf16(af, bf1, acc1, 0, 0, 0);

        // ---- step s+1 (uses qa; refill qa with s+3) ----
        f32x4 e0 = *(const f32x4*)(w0p + (s + 1) * 32);
        f32x4 e1 = *(const f32x4*)(w0p + (s + 1) * 32 + 4);
        f32x4 g0 = *(const f32x4*)(w1p + (s + 1) * 32);
        f32x4 g1 = *(const f32x4*)(w1p + (s + 1) * 32 + 4);
        short8 ag = cvt8(qa0, qa1);
        if (s + 3 < KH) {
            qa0 = *(const f32x4*)(xp + (s + 3) * 32);
            qa1 = *(const f32x4*)(xp + (s + 3) * 32 + 4);
        }
        short8 bg0 = cvt8(e0, e1);
        short8 bg1 = cvt8(g0, g1);
        acc0 = __builtin_amdgcn_mfma_f32_16x16x32_bf16(ag, bg0, acc0, 0, 0, 0);
        acc1 = __builtin_amdgcn_mfma_f32_16x16x32_bf16(ag, bg1, acc1, 0, 0, 0);
    }
    // tail: exactly 2 steps remain (KH even)
    {
        f32x4 c0 = *(const f32x4*)(w0p + s * 32);
        f32x4 c1 = *(const f32x4*)(w0p + s * 32 + 4);
        f32x4 d0 = *(const f32x4*)(w1p + s * 32);
        f32x4 d1 = *(const f32x4*)(w1p + s * 32 + 4);
        short8 af = cvt8(pa0, pa1);
        short8 bf0 = cvt8(c0, c1);
        short8 bf1 = cvt8(d0, d1);
        acc0 = __builtin_amdgcn_mfma_f32_16x16x32_bf16(af, bf0, acc0, 0, 0, 0);
        acc1 = __builtin_amdgcn_mfma_f32_16x16x32_bf16(af, bf1, acc1, 0, 0, 0);

        f32x4 e0 = *(const f32x4*)(w0p + (s + 1) * 32);
        f32x4 e1 = *(const f32x4*)(w0p + (s + 1) * 32 + 4);
        f32x4 g0 = *(const f32x4*)(w1p + (s + 1) * 32);
        f32x4 g1 = *(const f32x4*)(w1p + (s + 1) * 32 + 4);
        short8 ag = cvt8(qa0, qa1);
        short8 bg0 = cvt8(e0, e1);
        short8 bg1 = cvt8(g0, g1);
        acc0 = __builtin_amdgcn_mfma_f32_16x16x32_bf16(ag, bg0, acc0, 0, 0, 0);
        acc1 = __builtin_amdgcn_mfma_f32_16x16x32_bf16(ag, bg1, acc1, 0, 0, 0);
    }

    // write raw partial h to LDS
    // C/D layout: col = lane&15, row = (lane>>4)*4 + reg   [m89-verified]
    #pragma unroll
    for (int i = 0; i < 4; ++i) {
        hbuf[rg][kh][kg * 4 + i][lr]      = acc0[i];
        hbuf[rg][kh][kg * 4 + i][lr + 16] = acc1[i];
    }
    __syncthreads();

    // merge k-halves + bias + relu + layer 2 (kh==0 wave, lanes 0..31)
    if (kh == 0 && l < 32) {
        const int half = l >> 4;           // outputs 0..4 / 5..9
        const int row  = l & 15;
        const f32x4* hp0 = (const f32x4*)&hbuf[rg][0][row][0];
        const f32x4* hp1 = (const f32x4*)&hbuf[rg][1][row][0];
        const f32x4* bb  = (const f32x4*)b1;
        f32x4 hv[8];
        #pragma unroll
        for (int q = 0; q < 8; ++q) {
            f32x4 v = hp0[q] + hp1[q] + bb[q];
            #pragma unroll
            for (int j = 0; j < 4; ++j) v[j] = fmaxf(v[j], 0.f);
            hv[q] = v;
        }

        float* op = out + (size_t)(rowbase + row) * OUTS + half * 5;
        #pragma unroll
        for (int oo = 0; oo < 5; ++oo) {
            const int o = half * 5 + oo;
            const f32x4* w2p = (const f32x4*)(W2 + o * HIDDEN);
            f32x4 s4 = {0.f, 0.f, 0.f, 0.f};
            #pragma unroll
            for (int q = 0; q < 8; ++q) s4 += hv[q] * w2p[q];
            float v = b2[o] + s4[0] + s4[1] + s4[2] + s4[3];
            op[oo] = 1.0f / (1.0f + __expf(-v));
        }
    }
}

extern "C" void kernel_launch(void* const* d_in, const int* in_sizes, int n_in,
                              void* d_out, int out_size, void* d_ws, size_t ws_size,
                              hipStream_t stream) {
    (void)n_in; (void)out_size; (void)d_ws; (void)ws_size;
    const float* x  = (const float*)d_in[0];
    const float* W1 = (const float*)d_in[1];
    const float* b1 = (const float*)d_in[2];
    const float* W2 = (const float*)d_in[3];
    const float* b2 = (const float*)d_in[4];
    float* out = (float*)d_out;

    const int N = in_sizes[0] / IN_SIZE;       // 32768
    const int nblocks = N / 32;                // 1024

    mlp_one<<<dim3(nblocks), dim3(256), 0, stream>>>(x, W1, b1, W2, b2, out);
}

// Round 6
// 106.155 us; speedup vs baseline: 1.3522x; 1.3522x over previous
//
#include <hip/hip_runtime.h>
#include <hip/hip_bf16.h>

// x (32768,3072) f32, W1 (32,3072), b1 (32), W2 (10,32), b2 (10)
// out: (32768,10) f32 = sigmoid(relu(x@W1^T+b1)@W2^T+b2)
//
// R2 structure (best: 89.5 us) + NON-TEMPORAL x loads (nt bit) so the
// 403-MB x stream stops evicting the L2-resident 192-KB w1s fragments.

typedef float  f32x4  __attribute__((ext_vector_type(4)));
typedef short  short8 __attribute__((ext_vector_type(8)));

#define IN_SIZE 3072
#define HIDDEN  32
#define OUTS    10
#define KSPLIT  2
#define KH      (IN_SIZE / 32 / KSPLIT)   // 48 K-steps per wave

__device__ __forceinline__ unsigned short f2bf(float f) {
    return __builtin_bit_cast(unsigned short, __float2bfloat16(f));
}

__device__ __forceinline__ short8 cvt8(f32x4 a, f32x4 b) {
    short8 r;
    r[0] = (short)f2bf(a[0]); r[1] = (short)f2bf(a[1]);
    r[2] = (short)f2bf(a[2]); r[3] = (short)f2bf(a[3]);
    r[4] = (short)f2bf(b[0]); r[5] = (short)f2bf(b[1]);
    r[6] = (short)f2bf(b[2]); r[7] = (short)f2bf(b[3]);
    return r;
}

__device__ __forceinline__ f32x4 ntload4(const float* p) {
    return __builtin_nontemporal_load((const f32x4*)p);
}

// Pre-swizzle W1 (32x3072 f32) into bf16 B-fragment layout:
// frag index t = s*128 + nt*64 + lane ; element j (0..7):
//   value = W1[(lane&15)+16*nt][ s*32 + (lane>>4)*8 + j ]
__global__ void prep_w1(const float* __restrict__ W1,
                        unsigned short* __restrict__ w1s) {
    int t  = blockIdx.x * 256 + threadIdx.x;      // 0..12287
    int l  = t & 63;
    int nt = (t >> 6) & 1;
    int s  = t >> 7;
    int h  = (l & 15) + nt * 16;
    int k  = s * 32 + ((l >> 4) * 8);
    const float* src = W1 + (size_t)h * IN_SIZE + k;
    f32x4 f0 = *(const f32x4*)src;
    f32x4 f1 = *(const f32x4*)(src + 4);
    ((short8*)w1s)[t] = cvt8(f0, f1);
}

template <bool USE_WS>
__global__ __launch_bounds__(256, 4)
void mlp_fused(const float* __restrict__ x,
               const float* __restrict__ W1,
               const float* __restrict__ b1,
               const float* __restrict__ W2,
               const float* __restrict__ b2,
               const unsigned short* __restrict__ w1s,
               float* __restrict__ out) {
    // 2 rowgroups x 2 k-halves of partial h tiles (raw accumulators, no bias)
    __shared__ __align__(16) float hbuf[2][2][16][36];

    const int tid = threadIdx.x;
    const int l   = tid & 63;          // lane
    const int w   = tid >> 6;          // wave in block
    const int rg  = w >> 1;            // rowgroup (0..1)
    const int kh  = w & 1;             // k-half   (0..1)
    const int lr  = l & 15;            // A row within tile / C col
    const int kg  = l >> 4;            // k-group (0..3)
    const int rowbase = blockIdx.x * 32 + rg * 16;

    const float* xp = x + (size_t)(rowbase + lr) * IN_SIZE + kh * (KH * 32) + kg * 8;

    f32x4 acc0 = {0.f, 0.f, 0.f, 0.f};   // h cols 0..15
    f32x4 acc1 = {0.f, 0.f, 0.f, 0.f};   // h cols 16..31

    if constexpr (USE_WS) {
        const short8* wp = (const short8*)w1s + (size_t)kh * KH * 128 + l;
        // depth-2 register prefetch, named slots (no runtime-indexed arrays)
        f32x4 pa0 = ntload4(xp);
        f32x4 pa1 = ntload4(xp + 4);
        short8 pb0 = wp[0];
        short8 pb1 = wp[64];
        f32x4 qa0 = ntload4(xp + 32);
        f32x4 qa1 = ntload4(xp + 36);
        short8 qb0 = wp[128];
        short8 qb1 = wp[192];
        int s = 0;
        for (; s + 2 < KH; s += 2) {
            short8 af = cvt8(pa0, pa1);
            acc0 = __builtin_amdgcn_mfma_f32_16x16x32_bf16(af, pb0, acc0, 0, 0, 0);
            acc1 = __builtin_amdgcn_mfma_f32_16x16x32_bf16(af, pb1, acc1, 0, 0, 0);
            pa0 = ntload4(xp + (s + 2) * 32);
            pa1 = ntload4(xp + (s + 2) * 32 + 4);
            pb0 = wp[(s + 2) * 128];
            pb1 = wp[(s + 2) * 128 + 64];
            short8 ag = cvt8(qa0, qa1);
            acc0 = __builtin_amdgcn_mfma_f32_16x16x32_bf16(ag, qb0, acc0, 0, 0, 0);
            acc1 = __builtin_amdgcn_mfma_f32_16x16x32_bf16(ag, qb1, acc1, 0, 0, 0);
            if (s + 3 < KH) {
                qa0 = ntload4(xp + (s + 3) * 32);
                qa1 = ntload4(xp + (s + 3) * 32 + 4);
                qb0 = wp[(s + 3) * 128];
                qb1 = wp[(s + 3) * 128 + 64];
            }
        }
        // tail: exactly 2 steps remain (KH even)
        short8 af = cvt8(pa0, pa1);
        acc0 = __builtin_amdgcn_mfma_f32_16x16x32_bf16(af, pb0, acc0, 0, 0, 0);
        acc1 = __builtin_amdgcn_mfma_f32_16x16x32_bf16(af, pb1, acc1, 0, 0, 0);
        short8 ag = cvt8(qa0, qa1);
        acc0 = __builtin_amdgcn_mfma_f32_16x16x32_bf16(ag, qb0, acc0, 0, 0, 0);
        acc1 = __builtin_amdgcn_mfma_f32_16x16x32_bf16(ag, qb1, acc1, 0, 0, 0);
    } else {
        // fallback: load W1 f32 and convert in-register (depth-1)
        const float* w0p = W1 + (size_t)lr * IN_SIZE + kh * (KH * 32) + kg * 8;
        const float* w1p = W1 + (size_t)(lr + 16) * IN_SIZE + kh * (KH * 32) + kg * 8;
        f32x4 a0 = ntload4(xp);
        f32x4 a1 = ntload4(xp + 4);
        f32x4 c0 = *(const f32x4*)(w0p);
        f32x4 c1 = *(const f32x4*)(w0p + 4);
        f32x4 d0 = *(const f32x4*)(w1p);
        f32x4 d1 = *(const f32x4*)(w1p + 4);
        #pragma unroll 4
        for (int s = 0; s < KH; ++s) {
            const int sn = (s + 1 < KH) ? s + 1 : KH - 1;
            f32x4 na0 = ntload4(xp + sn * 32);
            f32x4 na1 = ntload4(xp + sn * 32 + 4);
            f32x4 nc0 = *(const f32x4*)(w0p + sn * 32);
            f32x4 nc1 = *(const f32x4*)(w0p + sn * 32 + 4);
            f32x4 nd0 = *(const f32x4*)(w1p + sn * 32);
            f32x4 nd1 = *(const f32x4*)(w1p + sn * 32 + 4);
            short8 af  = cvt8(a0, a1);
            short8 bf0 = cvt8(c0, c1);
            short8 bf1 = cvt8(d0, d1);
            acc0 = __builtin_amdgcn_mfma_f32_16x16x32_bf16(af, bf0, acc0, 0, 0, 0);
            acc1 = __builtin_amdgcn_mfma_f32_16x16x32_bf16(af, bf1, acc1, 0, 0, 0);
            a0 = na0; a1 = na1; c0 = nc0; c1 = nc1; d0 = nd0; d1 = nd1;
        }
    }

    // write raw partial h to LDS
    // C/D layout: col = lane&15, row = (lane>>4)*4 + reg   [m89-verified]
    #pragma unroll
    for (int i = 0; i < 4; ++i) {
        hbuf[rg][kh][kg * 4 + i][lr]      = acc0[i];
        hbuf[rg][kh][kg * 4 + i][lr + 16] = acc1[i];
    }
    __syncthreads();

    // merge k-halves + bias + relu + layer 2 (kh==0 wave, lanes 0..31)
    if (kh == 0 && l < 32) {
        const int half = l >> 4;           // outputs 0..4 / 5..9
        const int row  = l & 15;
        const f32x4* hp0 = (const f32x4*)&hbuf[rg][0][row][0];
        const f32x4* hp1 = (const f32x4*)&hbuf[rg][1][row][0];
        const f32x4* bb  = (const f32x4*)b1;
        f32x4 hv[8];
        #pragma unroll
        for (int q = 0; q < 8; ++q) {
            f32x4 v = hp0[q] + hp1[q] + bb[q];
            #pragma unroll
            for (int j = 0; j < 4; ++j) v[j] = fmaxf(v[j], 0.f);
            hv[q] = v;
        }

        const int rgrow = rowbase + row;
        float* op = out + (size_t)rgrow * OUTS + half * 5;
        #pragma unroll
        for (int oo = 0; oo < 5; ++oo) {
            const int o = half * 5 + oo;
            const f32x4* w2p = (const f32x4*)(W2 + o * HIDDEN);
            f32x4 s4 = {0.f, 0.f, 0.f, 0.f};
            #pragma unroll
            for (int q = 0; q < 8; ++q) s4 += hv[q] * w2p[q];
            float v = b2[o] + s4[0] + s4[1] + s4[2] + s4[3];
            op[oo] = 1.0f / (1.0f + __expf(-v));
        }
    }
}

extern "C" void kernel_launch(void* const* d_in, const int* in_sizes, int n_in,
                              void* d_out, int out_size, void* d_ws, size_t ws_size,
                              hipStream_t stream) {
    (void)n_in; (void)out_size;
    const float* x  = (const float*)d_in[0];
    const float* W1 = (const float*)d_in[1];
    const float* b1 = (const float*)d_in[2];
    const float* W2 = (const float*)d_in[3];
    const float* b2 = (const float*)d_in[4];
    float* out = (float*)d_out;

    const int N = in_sizes[0] / IN_SIZE;       // 32768
    const int nblocks = N / 32;                // 1024 (4 waves: 2 rowgroups x 2 k-halves)

    const size_t ws_needed = (size_t)(IN_SIZE / 32) * 128 * 16;   // 196608 B
    if (ws_size >= ws_needed) {
        unsigned short* w1s = (unsigned short*)d_ws;
        prep_w1<<<dim3(48), dim3(256), 0, stream>>>(W1, w1s);
        mlp_fused<true><<<dim3(nblocks), dim3(256), 0, stream>>>(
            x, W1, b1, W2, b2, w1s, out);
    } else {
        mlp_fused<false><<<dim3(nblocks), dim3(256), 0, stream>>>(
            x, W1, b1, W2, b2, nullptr, out);
    }
}

// Round 7
// 93.776 us; speedup vs baseline: 1.5306x; 1.1320x over previous
//
#include <hip/hip_runtime.h>
#include <hip/hip_bf16.h>

// x (32768,3072) f32, W1 (32,3072), b1 (32), W2 (10,32), b2 (10)
// out: (32768,10) f32 = sigmoid(relu(x@W1^T+b1)@W2^T+b2)
//
// R2 structure (best: 89.5 us) + per-block K-PHASE ROTATION:
// block b starts its K loop at step s0=2*(b%24) and wraps, so the
// device-wide instantaneous k-window covers all DRAM channel classes
// instead of a narrow lockstep slice.

typedef float  f32x4  __attribute__((ext_vector_type(4)));
typedef short  short8 __attribute__((ext_vector_type(8)));

#define IN_SIZE 3072
#define HIDDEN  32
#define OUTS    10
#define KSPLIT  2
#define KH      (IN_SIZE / 32 / KSPLIT)   // 48 K-steps per wave

__device__ __forceinline__ unsigned short f2bf(float f) {
    return __builtin_bit_cast(unsigned short, __float2bfloat16(f));
}

__device__ __forceinline__ short8 cvt8(f32x4 a, f32x4 b) {
    short8 r;
    r[0] = (short)f2bf(a[0]); r[1] = (short)f2bf(a[1]);
    r[2] = (short)f2bf(a[2]); r[3] = (short)f2bf(a[3]);
    r[4] = (short)f2bf(b[0]); r[5] = (short)f2bf(b[1]);
    r[6] = (short)f2bf(b[2]); r[7] = (short)f2bf(b[3]);
    return r;
}

// Pre-swizzle W1 (32x3072 f32) into bf16 B-fragment layout:
// frag index t = s*128 + nt*64 + lane ; element j (0..7):
//   value = W1[(lane&15)+16*nt][ s*32 + (lane>>4)*8 + j ]
__global__ void prep_w1(const float* __restrict__ W1,
                        unsigned short* __restrict__ w1s) {
    int t  = blockIdx.x * 256 + threadIdx.x;      // 0..12287
    int l  = t & 63;
    int nt = (t >> 6) & 1;
    int s  = t >> 7;
    int h  = (l & 15) + nt * 16;
    int k  = s * 32 + ((l >> 4) * 8);
    const float* src = W1 + (size_t)h * IN_SIZE + k;
    f32x4 f0 = *(const f32x4*)src;
    f32x4 f1 = *(const f32x4*)(src + 4);
    ((short8*)w1s)[t] = cvt8(f0, f1);
}

template <bool USE_WS>
__global__ __launch_bounds__(256, 4)
void mlp_fused(const float* __restrict__ x,
               const float* __restrict__ W1,
               const float* __restrict__ b1,
               const float* __restrict__ W2,
               const float* __restrict__ b2,
               const unsigned short* __restrict__ w1s,
               float* __restrict__ out) {
    // 2 rowgroups x 2 k-halves of partial h tiles (raw accumulators, no bias)
    __shared__ __align__(16) float hbuf[2][2][16][36];

    const int tid = threadIdx.x;
    const int l   = tid & 63;          // lane
    const int w   = tid >> 6;          // wave in block
    const int rg  = w >> 1;            // rowgroup (0..1)
    const int kh  = w & 1;             // k-half   (0..1)
    const int lr  = l & 15;            // A row within tile / C col
    const int kg  = l >> 4;            // k-group (0..3)
    const int rowbase = blockIdx.x * 32 + rg * 16;

    // per-block K-phase rotation (even so the 2-step pipeline stays aligned)
    const int s0 = 2 * (blockIdx.x % 24);
    auto widx = [&](int n) { int t = n + s0; return (t < KH) ? t : t - KH; };

    const float* xp = x + (size_t)(rowbase + lr) * IN_SIZE + kh * (KH * 32) + kg * 8;

    f32x4 acc0 = {0.f, 0.f, 0.f, 0.f};   // h cols 0..15
    f32x4 acc1 = {0.f, 0.f, 0.f, 0.f};   // h cols 16..31

    if constexpr (USE_WS) {
        const short8* wp = (const short8*)w1s + (size_t)kh * KH * 128 + l;
        // depth-2 register prefetch, named slots (no runtime-indexed arrays)
        const int i0 = widx(0), i1 = widx(1);
        f32x4 pa0 = *(const f32x4*)(xp + i0 * 32);
        f32x4 pa1 = *(const f32x4*)(xp + i0 * 32 + 4);
        short8 pb0 = wp[i0 * 128];
        short8 pb1 = wp[i0 * 128 + 64];
        f32x4 qa0 = *(const f32x4*)(xp + i1 * 32);
        f32x4 qa1 = *(const f32x4*)(xp + i1 * 32 + 4);
        short8 qb0 = wp[i1 * 128];
        short8 qb1 = wp[i1 * 128 + 64];
        int s = 0;
        for (; s + 2 < KH; s += 2) {
            const int n2 = widx(s + 2);
            const int n3 = widx(s + 3);
            short8 af = cvt8(pa0, pa1);
            acc0 = __builtin_amdgcn_mfma_f32_16x16x32_bf16(af, pb0, acc0, 0, 0, 0);
            acc1 = __builtin_amdgcn_mfma_f32_16x16x32_bf16(af, pb1, acc1, 0, 0, 0);
            pa0 = *(const f32x4*)(xp + n2 * 32);
            pa1 = *(const f32x4*)(xp + n2 * 32 + 4);
            pb0 = wp[n2 * 128];
            pb1 = wp[n2 * 128 + 64];
            short8 ag = cvt8(qa0, qa1);
            acc0 = __builtin_amdgcn_mfma_f32_16x16x32_bf16(ag, qb0, acc0, 0, 0, 0);
            acc1 = __builtin_amdgcn_mfma_f32_16x16x32_bf16(ag, qb1, acc1, 0, 0, 0);
            qa0 = *(const f32x4*)(xp + n3 * 32);
            qa1 = *(const f32x4*)(xp + n3 * 32 + 4);
            qb0 = wp[n3 * 128];
            qb1 = wp[n3 * 128 + 64];
        }
        // tail: exactly 2 steps remain (KH even)
        short8 af = cvt8(pa0, pa1);
        acc0 = __builtin_amdgcn_mfma_f32_16x16x32_bf16(af, pb0, acc0, 0, 0, 0);
        acc1 = __builtin_amdgcn_mfma_f32_16x16x32_bf16(af, pb1, acc1, 0, 0, 0);
        short8 ag = cvt8(qa0, qa1);
        acc0 = __builtin_amdgcn_mfma_f32_16x16x32_bf16(ag, qb0, acc0, 0, 0, 0);
        acc1 = __builtin_amdgcn_mfma_f32_16x16x32_bf16(ag, qb1, acc1, 0, 0, 0);
    } else {
        // fallback: load W1 f32 and convert in-register (depth-1)
        const float* w0p = W1 + (size_t)lr * IN_SIZE + kh * (KH * 32) + kg * 8;
        const float* w1p = W1 + (size_t)(lr + 16) * IN_SIZE + kh * (KH * 32) + kg * 8;
        #pragma unroll 4
        for (int s = 0; s < KH; ++s) {
            f32x4 a0 = *(const f32x4*)(xp + s * 32);
            f32x4 a1 = *(const f32x4*)(xp + s * 32 + 4);
            f32x4 c0 = *(const f32x4*)(w0p + s * 32);
            f32x4 c1 = *(const f32x4*)(w0p + s * 32 + 4);
            f32x4 d0 = *(const f32x4*)(w1p + s * 32);
            f32x4 d1 = *(const f32x4*)(w1p + s * 32 + 4);
            short8 af  = cvt8(a0, a1);
            short8 bf0 = cvt8(c0, c1);
            short8 bf1 = cvt8(d0, d1);
            acc0 = __builtin_amdgcn_mfma_f32_16x16x32_bf16(af, bf0, acc0, 0, 0, 0);
            acc1 = __builtin_amdgcn_mfma_f32_16x16x32_bf16(af, bf1, acc1, 0, 0, 0);
        }
    }

    // write raw partial h to LDS
    // C/D layout: col = lane&15, row = (lane>>4)*4 + reg   [m89-verified]
    #pragma unroll
    for (int i = 0; i < 4; ++i) {
        hbuf[rg][kh][kg * 4 + i][lr]      = acc0[i];
        hbuf[rg][kh][kg * 4 + i][lr + 16] = acc1[i];
    }
    __syncthreads();

    // merge k-halves + bias + relu + layer 2 (kh==0 wave, lanes 0..31)
    if (kh == 0 && l < 32) {
        const int half = l >> 4;           // outputs 0..4 / 5..9
        const int row  = l & 15;
        const f32x4* hp0 = (const f32x4*)&hbuf[rg][0][row][0];
        const f32x4* hp1 = (const f32x4*)&hbuf[rg][1][row][0];
        const f32x4* bb  = (const f32x4*)b1;
        f32x4 hv[8];
        #pragma unroll
        for (int q = 0; q < 8; ++q) {
            f32x4 v = hp0[q] + hp1[q] + bb[q];
            #pragma unroll
            for (int j = 0; j < 4; ++j) v[j] = fmaxf(v[j], 0.f);
            hv[q] = v;
        }

        float* op = out + (size_t)(rowbase + row) * OUTS + half * 5;
        #pragma unroll
        for (int oo = 0; oo < 5; ++oo) {
            const int o = half * 5 + oo;
            const f32x4* w2p = (const f32x4*)(W2 + o * HIDDEN);
            f32x4 s4 = {0.f, 0.f, 0.f, 0.f};
            #pragma unroll
            for (int q = 0; q < 8; ++q) s4 += hv[q] * w2p[q];
            float v = b2[o] + s4[0] + s4[1] + s4[2] + s4[3];
            op[oo] = 1.0f / (1.0f + __expf(-v));
        }
    }
}

extern "C" void kernel_launch(void* const* d_in, const int* in_sizes, int n_in,
                              void* d_out, int out_size, void* d_ws, size_t ws_size,
                              hipStream_t stream) {
    (void)n_in; (void)out_size;
    const float* x  = (const float*)d_in[0];
    const float* W1 = (const float*)d_in[1];
    const float* b1 = (const float*)d_in[2];
    const float* W2 = (const float*)d_in[3];
    const float* b2 = (const float*)d_in[4];
    float* out = (float*)d_out;

    const int N = in_sizes[0] / IN_SIZE;       // 32768
    const int nblocks = N / 32;                // 1024 (4 waves: 2 rowgroups x 2 k-halves)

    const size_t ws_needed = (size_t)(IN_SIZE / 32) * 128 * 16;   // 196608 B
    if (ws_size >= ws_needed) {
        unsigned short* w1s = (unsigned short*)d_ws;
        prep_w1<<<dim3(48), dim3(256), 0, stream>>>(W1, w1s);
        mlp_fused<true><<<dim3(nblocks), dim3(256), 0, stream>>>(
            x, W1, b1, W2, b2, w1s, out);
    } else {
        mlp_fused<false><<<dim3(nblocks), dim3(256), 0, stream>>>(
            x, W1, b1, W2, b2, nullptr, out);
    }
}

// Round 8
// 89.452 us; speedup vs baseline: 1.6046x; 1.0483x over previous
//
#include <hip/hip_runtime.h>
#include <hip/hip_bf16.h>

// x (32768,3072) f32, W1 (32,3072), b1 (32), W2 (10,32), b2 (10)
// out: (32768,10) f32 = sigmoid(relu(x@W1^T+b1)@W2^T+b2)
//
// FINAL (R2 structure, best measured 89.5 us):
//   - W1 pre-swizzled to bf16 MFMA B-fragments (prep_w1, L2-resident after)
//   - 4 waves/block = 2 rowgroups x 2 k-halves, 32 rows/block, 1024 blocks
//   - depth-2 register prefetch on the x stream, bf16 MFMA 16x16x32
//   - partial-h merge through LDS, fused bias+relu+layer2+sigmoid epilogue
// Roofline: 403 MB single-pass x read @ ~4.9 TB/s effective read rate
// (pattern-insensitive plateau verified across R1-R7 variants).

typedef float  f32x4  __attribute__((ext_vector_type(4)));
typedef short  short8 __attribute__((ext_vector_type(8)));

#define IN_SIZE 3072
#define HIDDEN  32
#define OUTS    10
#define KSPLIT  2
#define KH      (IN_SIZE / 32 / KSPLIT)   // 48 K-steps per wave

__device__ __forceinline__ unsigned short f2bf(float f) {
    return __builtin_bit_cast(unsigned short, __float2bfloat16(f));
}

__device__ __forceinline__ short8 cvt8(f32x4 a, f32x4 b) {
    short8 r;
    r[0] = (short)f2bf(a[0]); r[1] = (short)f2bf(a[1]);
    r[2] = (short)f2bf(a[2]); r[3] = (short)f2bf(a[3]);
    r[4] = (short)f2bf(b[0]); r[5] = (short)f2bf(b[1]);
    r[6] = (short)f2bf(b[2]); r[7] = (short)f2bf(b[3]);
    return r;
}

// Pre-swizzle W1 (32x3072 f32) into bf16 B-fragment layout:
// frag index t = s*128 + nt*64 + lane ; element j (0..7):
//   value = W1[(lane&15)+16*nt][ s*32 + (lane>>4)*8 + j ]
__global__ void prep_w1(const float* __restrict__ W1,
                        unsigned short* __restrict__ w1s) {
    int t  = blockIdx.x * 256 + threadIdx.x;      // 0..12287
    int l  = t & 63;
    int nt = (t >> 6) & 1;
    int s  = t >> 7;
    int h  = (l & 15) + nt * 16;
    int k  = s * 32 + ((l >> 4) * 8);
    const float* src = W1 + (size_t)h * IN_SIZE + k;
    f32x4 f0 = *(const f32x4*)src;
    f32x4 f1 = *(const f32x4*)(src + 4);
    ((short8*)w1s)[t] = cvt8(f0, f1);
}

template <bool USE_WS>
__global__ __launch_bounds__(256, 4)
void mlp_fused(const float* __restrict__ x,
               const float* __restrict__ W1,
               const float* __restrict__ b1,
               const float* __restrict__ W2,
               const float* __restrict__ b2,
               const unsigned short* __restrict__ w1s,
               float* __restrict__ out) {
    // 2 rowgroups x 2 k-halves of partial h tiles (raw accumulators, no bias)
    __shared__ __align__(16) float hbuf[2][2][16][36];

    const int tid = threadIdx.x;
    const int l   = tid & 63;          // lane
    const int w   = tid >> 6;          // wave in block
    const int rg  = w >> 1;            // rowgroup (0..1)
    const int kh  = w & 1;             // k-half   (0..1)
    const int lr  = l & 15;            // A row within tile / C col
    const int kg  = l >> 4;            // k-group (0..3)
    const int rowbase = blockIdx.x * 32 + rg * 16;

    const float* xp = x + (size_t)(rowbase + lr) * IN_SIZE + kh * (KH * 32) + kg * 8;

    f32x4 acc0 = {0.f, 0.f, 0.f, 0.f};   // h cols 0..15
    f32x4 acc1 = {0.f, 0.f, 0.f, 0.f};   // h cols 16..31

    if constexpr (USE_WS) {
        const short8* wp = (const short8*)w1s + (size_t)kh * KH * 128 + l;
        // depth-2 register prefetch, named slots (no runtime-indexed arrays)
        f32x4 pa0 = *(const f32x4*)(xp);
        f32x4 pa1 = *(const f32x4*)(xp + 4);
        short8 pb0 = wp[0];
        short8 pb1 = wp[64];
        f32x4 qa0 = *(const f32x4*)(xp + 32);
        f32x4 qa1 = *(const f32x4*)(xp + 36);
        short8 qb0 = wp[128];
        short8 qb1 = wp[192];
        int s = 0;
        for (; s + 2 < KH; s += 2) {
            short8 af = cvt8(pa0, pa1);
            acc0 = __builtin_amdgcn_mfma_f32_16x16x32_bf16(af, pb0, acc0, 0, 0, 0);
            acc1 = __builtin_amdgcn_mfma_f32_16x16x32_bf16(af, pb1, acc1, 0, 0, 0);
            pa0 = *(const f32x4*)(xp + (s + 2) * 32);
            pa1 = *(const f32x4*)(xp + (s + 2) * 32 + 4);
            pb0 = wp[(s + 2) * 128];
            pb1 = wp[(s + 2) * 128 + 64];
            short8 ag = cvt8(qa0, qa1);
            acc0 = __builtin_amdgcn_mfma_f32_16x16x32_bf16(ag, qb0, acc0, 0, 0, 0);
            acc1 = __builtin_amdgcn_mfma_f32_16x16x32_bf16(ag, qb1, acc1, 0, 0, 0);
            if (s + 3 < KH) {
                qa0 = *(const f32x4*)(xp + (s + 3) * 32);
                qa1 = *(const f32x4*)(xp + (s + 3) * 32 + 4);
                qb0 = wp[(s + 3) * 128];
                qb1 = wp[(s + 3) * 128 + 64];
            }
        }
        // tail: exactly 2 steps remain (KH even)
        short8 af = cvt8(pa0, pa1);
        acc0 = __builtin_amdgcn_mfma_f32_16x16x32_bf16(af, pb0, acc0, 0, 0, 0);
        acc1 = __builtin_amdgcn_mfma_f32_16x16x32_bf16(af, pb1, acc1, 0, 0, 0);
        short8 ag = cvt8(qa0, qa1);
        acc0 = __builtin_amdgcn_mfma_f32_16x16x32_bf16(ag, qb0, acc0, 0, 0, 0);
        acc1 = __builtin_amdgcn_mfma_f32_16x16x32_bf16(ag, qb1, acc1, 0, 0, 0);
    } else {
        // fallback: load W1 f32 and convert in-register (depth-1)
        const float* w0p = W1 + (size_t)lr * IN_SIZE + kh * (KH * 32) + kg * 8;
        const float* w1p = W1 + (size_t)(lr + 16) * IN_SIZE + kh * (KH * 32) + kg * 8;
        f32x4 a0 = *(const f32x4*)(xp);
        f32x4 a1 = *(const f32x4*)(xp + 4);
        f32x4 c0 = *(const f32x4*)(w0p);
        f32x4 c1 = *(const f32x4*)(w0p + 4);
        f32x4 d0 = *(const f32x4*)(w1p);
        f32x4 d1 = *(const f32x4*)(w1p + 4);
        #pragma unroll 4
        for (int s = 0; s < KH; ++s) {
            const int sn = (s + 1 < KH) ? s + 1 : KH - 1;
            f32x4 na0 = *(const f32x4*)(xp + sn * 32);
            f32x4 na1 = *(const f32x4*)(xp + sn * 32 + 4);
            f32x4 nc0 = *(const f32x4*)(w0p + sn * 32);
            f32x4 nc1 = *(const f32x4*)(w0p + sn * 32 + 4);
            f32x4 nd0 = *(const f32x4*)(w1p + sn * 32);
            f32x4 nd1 = *(const f32x4*)(w1p + sn * 32 + 4);
            short8 af  = cvt8(a0, a1);
            short8 bf0 = cvt8(c0, c1);
            short8 bf1 = cvt8(d0, d1);
            acc0 = __builtin_amdgcn_mfma_f32_16x16x32_bf16(af, bf0, acc0, 0, 0, 0);
            acc1 = __builtin_amdgcn_mfma_f32_16x16x32_bf16(af, bf1, acc1, 0, 0, 0);
            a0 = na0; a1 = na1; c0 = nc0; c1 = nc1; d0 = nd0; d1 = nd1;
        }
    }

    // write raw partial h to LDS
    // C/D layout: col = lane&15, row = (lane>>4)*4 + reg   [m89-verified]
    #pragma unroll
    for (int i = 0; i < 4; ++i) {
        hbuf[rg][kh][kg * 4 + i][lr]      = acc0[i];
        hbuf[rg][kh][kg * 4 + i][lr + 16] = acc1[i];
    }
    __syncthreads();

    // merge k-halves + bias + relu + layer 2 (kh==0 wave, lanes 0..31)
    if (kh == 0 && l < 32) {
        const int half = l >> 4;           // outputs 0..4 / 5..9
        const int row  = l & 15;
        const f32x4* hp0 = (const f32x4*)&hbuf[rg][0][row][0];
        const f32x4* hp1 = (const f32x4*)&hbuf[rg][1][row][0];
        const f32x4* bb  = (const f32x4*)b1;
        f32x4 hv[8];
        #pragma unroll
        for (int q = 0; q < 8; ++q) {
            f32x4 v = hp0[q] + hp1[q] + bb[q];
            #pragma unroll
            for (int j = 0; j < 4; ++j) v[j] = fmaxf(v[j], 0.f);
            hv[q] = v;
        }

        float* op = out + (size_t)(rowbase + row) * OUTS + half * 5;
        #pragma unroll
        for (int oo = 0; oo < 5; ++oo) {
            const int o = half * 5 + oo;
            const f32x4* w2p = (const f32x4*)(W2 + o * HIDDEN);
            f32x4 s4 = {0.f, 0.f, 0.f, 0.f};
            #pragma unroll
            for (int q = 0; q < 8; ++q) s4 += hv[q] * w2p[q];
            float v = b2[o] + s4[0] + s4[1] + s4[2] + s4[3];
            op[oo] = 1.0f / (1.0f + __expf(-v));
        }
    }
}

extern "C" void kernel_launch(void* const* d_in, const int* in_sizes, int n_in,
                              void* d_out, int out_size, void* d_ws, size_t ws_size,
                              hipStream_t stream) {
    (void)n_in; (void)out_size;
    const float* x  = (const float*)d_in[0];
    const float* W1 = (const float*)d_in[1];
    const float* b1 = (const float*)d_in[2];
    const float* W2 = (const float*)d_in[3];
    const float* b2 = (const float*)d_in[4];
    float* out = (float*)d_out;

    const int N = in_sizes[0] / IN_SIZE;       // 32768
    const int nblocks = N / 32;                // 1024 (4 waves: 2 rowgroups x 2 k-halves)

    const size_t ws_needed = (size_t)(IN_SIZE / 32) * 128 * 16;   // 196608 B
    if (ws_size >= ws_needed) {
        unsigned short* w1s = (unsigned short*)d_ws;
        prep_w1<<<dim3(48), dim3(256), 0, stream>>>(W1, w1s);
        mlp_fused<true><<<dim3(nblocks), dim3(256), 0, stream>>>(
            x, W1, b1, W2, b2, w1s, out);
    } else {
        mlp_fused<false><<<dim3(nblocks), dim3(256), 0, stream>>>(
            x, W1, b1, W2, b2, nullptr, out);
    }
}